// Round 4
// baseline (577.614 us; speedup 1.0000x reference)
//
#include <hip/hip_runtime.h>
#include <hip/hip_bf16.h>
#include <cstdint>
#include <type_traits>

#define D_MODEL 2048
#define NH 16
#define HD 128
#define SEQ 2048
#define QKV_LD (3 * D_MODEL) // 6144

typedef __attribute__((ext_vector_type(8))) short short8;
typedef __attribute__((ext_vector_type(4))) float f32x4;
typedef __attribute__((ext_vector_type(16))) float f32x16;

__device__ __forceinline__ ushort f2bf(float f) {
    union { float f; uint32_t u; } c; c.f = f;
    uint32_t u = c.u;
    uint32_t r = (u + 0x7FFFu + ((u >> 16) & 1u)) >> 16;
    return (ushort)r;
}
__device__ __forceinline__ float bf2f(ushort b) {
    union { uint32_t u; float f; } c; c.u = ((uint32_t)b) << 16;
    return c.f;
}

// ---------------- fp32 -> bf16 cast (x) ----------------
__global__ void cvt_bf16_kernel(const float* __restrict__ in, ushort* __restrict__ out, int n4) {
    int idx = blockIdx.x * blockDim.x + threadIdx.x;
    if (idx >= n4) return;
    float4 v = ((const float4*)in)[idx];
    ushort4 o;
    o.x = f2bf(v.x); o.y = f2bf(v.y); o.z = f2bf(v.z); o.w = f2bf(v.w);
    ((ushort4*)out)[idx] = o;
}

// ---------------- fp32 [R][C] -> bf16 [C][R] transpose ----------------
__global__ void transpose_bf16_kernel(const float* __restrict__ in, ushort* __restrict__ out,
                                      int R, int C) {
    __shared__ float tile[32][33];
    int tx = threadIdx.x, ty = threadIdx.y; // 32 x 8
    int c0 = blockIdx.x * 32, r0 = blockIdx.y * 32;
    for (int i = 0; i < 4; ++i) {
        int r = r0 + ty + i * 8;
        tile[ty + i * 8][tx] = in[(size_t)r * C + c0 + tx];
    }
    __syncthreads();
    for (int i = 0; i < 4; ++i) {
        int c = c0 + ty + i * 8;
        out[(size_t)c * R + r0 + tx] = f2bf(tile[tx][ty + i * 8]);
    }
}

// ---------------- bf16 MFMA GEMM, VGPR-prefetch pipeline ----------------
// C[M][N] = A[M][K] * Bt[N][K]^T + bias ; 128x128 tile, BK=32, 4 waves
// Loads for tile k+1 issued right after B2 of tile k (full-iter cover; VGPR
// loads survive barriers — no vmcnt drain until the consuming ds_write).
template <typename OutT>
__global__ __launch_bounds__(256) void gemm_bt_bias(
    const ushort* __restrict__ A,   // [M][K] bf16
    const ushort* __restrict__ Bt,  // [N][K] bf16
    const float* __restrict__ bias, // [N]
    OutT* __restrict__ C,           // [M][N] fp32 or bf16
    int M, int N, int K)
{
    __shared__ __align__(16) ushort As[128 * 32];
    __shared__ __align__(16) ushort Bs[128 * 32];
    int t = threadIdx.x;
    int m0 = blockIdx.y * 128, n0 = blockIdx.x * 128;
    int wave = t >> 6, lane = t & 63;
    int wm = (wave & 1) * 64, wn = (wave >> 1) * 64;
    int lr = lane & 15, lh = lane >> 4;

    f32x4 acc[4][4];
    for (int i = 0; i < 4; i++)
        for (int j = 0; j < 4; j++)
            acc[i][j] = (f32x4)0.0f;

    int srow = t >> 2;
    int scol = (t & 3) * 8;
    const ushort* Ag = A + (size_t)(m0 + srow) * K + scol;
    const ushort* Bg = Bt + (size_t)(n0 + srow) * K + scol;

    uint4 ar0 = *(const uint4*)(Ag);
    uint4 ar1 = *(const uint4*)(Ag + (size_t)64 * K);
    uint4 br0 = *(const uint4*)(Bg);
    uint4 br1 = *(const uint4*)(Bg + (size_t)64 * K);

    for (int k0 = 0; k0 < K; k0 += 32) {
        __syncthreads();
        *(uint4*)(As + srow * 32 + scol) = ar0;
        *(uint4*)(As + (srow + 64) * 32 + scol) = ar1;
        *(uint4*)(Bs + srow * 32 + scol) = br0;
        *(uint4*)(Bs + (srow + 64) * 32 + scol) = br1;
        __syncthreads();
        if (k0 + 32 < K) {
            ar0 = *(const uint4*)(Ag + k0 + 32);
            ar1 = *(const uint4*)(Ag + (size_t)64 * K + k0 + 32);
            br0 = *(const uint4*)(Bg + k0 + 32);
            br1 = *(const uint4*)(Bg + (size_t)64 * K + k0 + 32);
        }
        short8 a[4], b[4];
        for (int i = 0; i < 4; i++)
            a[i] = *(const short8*)(As + (wm + i * 16 + lr) * 32 + lh * 8);
        for (int j = 0; j < 4; j++)
            b[j] = *(const short8*)(Bs + (wn + j * 16 + lr) * 32 + lh * 8);
        for (int i = 0; i < 4; i++)
            for (int j = 0; j < 4; j++)
                acc[i][j] = __builtin_amdgcn_mfma_f32_16x16x32_bf16(a[i], b[j], acc[i][j], 0, 0, 0);
    }

    for (int i = 0; i < 4; i++) {
        int row = m0 + wm + i * 16 + lh * 4;
        for (int j = 0; j < 4; j++) {
            int col = n0 + wn + j * 16 + lr;
            float bv = bias[col];
            for (int r = 0; r < 4; r++) {
                float v = acc[i][j][r] + bv;
                if constexpr (std::is_same<OutT, ushort>::value)
                    C[(size_t)(row + r) * N + col] = f2bf(v);
                else
                    C[(size_t)(row + r) * N + col] = v;
            }
        }
    }
}

// ---------------- RoPE + cast + reshape: qkv_bf16 -> Qb,Kb [bh][s][128] (linear) ----------------
// Q pre-scaled by 1/sqrt(HD). One wave per 128-dim head vector.
__global__ void rope_cast_qk(const ushort* __restrict__ qkv,
                             ushort* __restrict__ Qb, ushort* __restrict__ Kb) {
    int t = threadIdx.x;
    int wv = blockIdx.x * 4 + (t >> 6); // 0..131071
    int j = t & 63;
    int bs = wv >> 5;
    int rem = wv & 31;
    int which = rem >> 4;  // 0=q, 1=k (wave-uniform)
    int h = rem & 15;
    int s = bs & 2047;
    int b = bs >> 11;
    size_t src = (size_t)bs * QKV_LD + which * D_MODEL + h * HD;
    uint32_t pr = *(const uint32_t*)(qkv + src + 2 * j);
    float x1 = bf2f((ushort)(pr & 0xffff));
    float x2 = bf2f((ushort)(pr >> 16));
    float theta = powf(10000.0f, -(float)j * (1.0f / 64.0f));
    float ang = (float)s * theta;
    float sn, cs;
    sincosf(ang, &sn, &cs);
    float sc = which ? 1.0f : 0.08838834764831845f;
    float o1 = (x1 * cs - x2 * sn) * sc;
    float o2 = (x1 * sn + x2 * cs) * sc;
    ushort* dst = which ? Kb : Qb;
    size_t obase = ((size_t)(b * NH + h) * SEQ + s) * HD;
    dst[obase + j] = f2bf(o1);
    dst[obase + 64 + j] = f2bf(o2);
}

// ---------------- V transpose: qkv_bf16 v-part -> Vt [bh][d=128][s=2048] (linear) ----------------
__global__ void v_transpose(const ushort* __restrict__ qkv, ushort* __restrict__ Vt) {
    __shared__ ushort tile[32][33];
    int tx = threadIdx.x, ty = threadIdx.y; // 32 x 8
    int s0 = blockIdx.x * 32;
    int d0 = blockIdx.y * 32;
    int bh = blockIdx.z;
    int b = bh >> 4, h = bh & 15;
    for (int i = 0; i < 4; ++i) {
        int s = s0 + ty + i * 8;
        tile[ty + i * 8][tx] = qkv[((size_t)(b * SEQ + s)) * QKV_LD + 2 * D_MODEL + h * HD + d0 + tx];
    }
    __syncthreads();
    for (int i = 0; i < 4; ++i) {
        int d = d0 + ty + i * 8;
        Vt[((size_t)bh * HD + d) * SEQ + s0 + tx] = tile[tx][ty + i * 8];
    }
}

// ---------------- MFMA flash attention, VGPR-prefetch pipeline ----------------
// 4 waves x 32q (q-tile 128), key-tile 64, single-buffered LDS (50 KB -> 2 blocks/CU).
// Per iter: B1 -> store regs->LDS -> B2 -> issue loads(i+1) -> S^T+softmax+PV.
__global__ __launch_bounds__(256, 2) void attn_mfma(const ushort* __restrict__ Qb,
                                                    const ushort* __restrict__ Kb,
                                                    const ushort* __restrict__ Vt,
                                                    ushort* __restrict__ ctx) {
    __shared__ __align__(16) ushort smem[25600]; // Ks[0,8192) Vts[8192,16384) Ps[16384,25600)
    ushort* Ks  = smem;          // [64][128], chunk c at c^(r&15)
    ushort* Vts = smem + 8192;   // [128][64], chunk c at c^(d&7)
    ushort* Ps  = smem + 16384;  // [128][72]

    int t = threadIdx.x;
    int w = t >> 6, l = t & 63;
    int l31 = l & 31, g = l >> 5;
    int q0 = blockIdx.x * 128;
    int bh = blockIdx.y;
    int b = bh >> 4, h = bh & 15;

    const ushort* KgB = Kb + (size_t)bh * SEQ * HD;
    const ushort* VtB = Vt + (size_t)bh * HD * SEQ;

    int qrow = q0 + w * 32 + l31;
    const ushort* Qg = Qb + ((size_t)bh * SEQ + qrow) * HD;
    short8 qf[8];
#pragma unroll
    for (int kc = 0; kc < 8; kc++)
        qf[kc] = *(const short8*)(Qg + kc * 16 + g * 8);

    f32x16 O[4];
#pragma unroll
    for (int di = 0; di < 4; di++) O[di] = (f32x16)0.0f;
    float m_run = -INFINITY, l_run = 0.0f;

    // staging geometry: 16 KB K + 16 KB V per tile, 4 x uint4 each per thread
    int offKg[4], offKl[4], offVg[4], offVl[4];
#pragma unroll
    for (int c2 = 0; c2 < 4; c2++) {
        int f = c2 * 256 + t;
        int r = f >> 4, c = f & 15;
        offKg[c2] = r * HD + c * 8;
        offKl[c2] = r * 128 + (c ^ (r & 15)) * 8;
        int d = f >> 3, cv = f & 7;
        offVg[c2] = d * SEQ + cv * 8;
        offVl[c2] = d * 64 + (cv ^ (d & 7)) * 8;
    }
    uint4 kreg[4], vreg[4];
#pragma unroll
    for (int c2 = 0; c2 < 4; c2++) {
        kreg[c2] = *(const uint4*)(KgB + offKg[c2]);
        vreg[c2] = *(const uint4*)(VtB + offVg[c2]);
    }

    for (int it = 0; it < SEQ / 64; it++) {
        int k0 = it * 64;
        __syncthreads(); // B1: prev iter's LDS consumers done
#pragma unroll
        for (int c2 = 0; c2 < 4; c2++) {
            *(uint4*)(Ks + offKl[c2]) = kreg[c2];
            *(uint4*)(Vts + offVl[c2]) = vreg[c2];
        }
        __syncthreads(); // B2: tiles visible
        if (it + 1 < SEQ / 64) {
#pragma unroll
            for (int c2 = 0; c2 < 4; c2++) {
                kreg[c2] = *(const uint4*)(KgB + (size_t)(k0 + 64) * HD + offKg[c2]);
                vreg[c2] = *(const uint4*)(VtB + (k0 + 64) + offVg[c2]);
            }
        }

        // S^T = K · Q^T : [64 keys][32 q] per wave, 2 tiles of 32x32
        f32x16 St[2];
        St[0] = (f32x16)0.0f;
        St[1] = (f32x16)0.0f;
#pragma unroll
        for (int ki = 0; ki < 2; ki++) {
            int row = ki * 32 + l31;
#pragma unroll
            for (int kc = 0; kc < 8; kc++) {
                int cp = (kc * 2 + g) ^ (row & 15);
                short8 a = *(const short8*)(Ks + row * 128 + cp * 8);
                St[ki] = __builtin_amdgcn_mfma_f32_32x32x16_bf16(a, qf[kc], St[ki], 0, 0, 0);
            }
        }

        // online softmax (keys in regs, q = lane)
        float mx = -INFINITY;
#pragma unroll
        for (int ki = 0; ki < 2; ki++)
#pragma unroll
            for (int r = 0; r < 16; r++) mx = fmaxf(mx, St[ki][r]);
        mx = fmaxf(mx, __shfl_xor(mx, 32));
        float mn = fmaxf(m_run, mx);
        float alpha = __expf(m_run - mn);
        m_run = mn;
        float psum = 0.0f;
#pragma unroll
        for (int ki = 0; ki < 2; ki++)
#pragma unroll
            for (int r = 0; r < 16; r++) {
                float p = __expf(St[ki][r] - mn);
                St[ki][r] = p;
                psum += p;
            }
        psum += __shfl_xor(psum, 32);
        l_run = l_run * alpha + psum;
#pragma unroll
        for (int di = 0; di < 4; di++)
#pragma unroll
            for (int r = 0; r < 16; r++) O[di][r] *= alpha;

        // P (bf16) -> LDS, wave-private rows (same-wave LDS ordering; no barrier)
        {
            int qloc = w * 32 + l31;
            ushort* Pr = Ps + qloc * 72;
#pragma unroll
            for (int ki = 0; ki < 2; ki++)
#pragma unroll
                for (int u = 0; u < 4; u++) {
                    ushort4 pk;
                    pk.x = f2bf(St[ki][4 * u + 0]);
                    pk.y = f2bf(St[ki][4 * u + 1]);
                    pk.z = f2bf(St[ki][4 * u + 2]);
                    pk.w = f2bf(St[ki][4 * u + 3]);
                    *(ushort4*)(Pr + ki * 32 + 8 * u + 4 * g) = pk;
                }
        }

        // O^T += V^T · P^T : [128 d][32 q] per wave
        {
            int qloc = w * 32 + l31;
            short8 pb[4];
#pragma unroll
            for (int kc = 0; kc < 4; kc++)
                pb[kc] = *(const short8*)(Ps + qloc * 72 + kc * 16 + g * 8);
#pragma unroll
            for (int di = 0; di < 4; di++) {
                int d = di * 32 + l31;
#pragma unroll
                for (int kc = 0; kc < 4; kc++) {
                    int cp = (kc * 2 + g) ^ (d & 7);
                    short8 va = *(const short8*)(Vts + d * 64 + cp * 8);
                    O[di] = __builtin_amdgcn_mfma_f32_32x32x16_bf16(va, pb[kc], O[di], 0, 0, 0);
                }
            }
        }
    }

    // epilogue: normalize, transpose through LDS, coalesced store
    __syncthreads();
    float inv = 1.0f / l_run;
    ushort* ob = smem; // [128][128]
    {
        int qloc = w * 32 + l31;
        ushort* orow = ob + qloc * 128;
#pragma unroll
        for (int di = 0; di < 4; di++)
#pragma unroll
            for (int u = 0; u < 4; u++) {
                ushort4 pk;
                pk.x = f2bf(O[di][4 * u + 0] * inv);
                pk.y = f2bf(O[di][4 * u + 1] * inv);
                pk.z = f2bf(O[di][4 * u + 2] * inv);
                pk.w = f2bf(O[di][4 * u + 3] * inv);
                *(ushort4*)(orow + di * 32 + 8 * u + 4 * g) = pk;
            }
    }
#pragma unroll
    for (int p = 0; p < 8; p++) {
        int qloc = w * 32 + p * 4 + (l >> 4);
        int c16 = l & 15;
        uint4 v = *(const uint4*)(ob + qloc * 128 + c16 * 8);
        size_t tok = (size_t)b * SEQ + q0 + qloc;
        *(uint4*)(ctx + tok * D_MODEL + h * HD + c16 * 8) = v;
    }
}

extern "C" void kernel_launch(void* const* d_in, const int* in_sizes, int n_in,
                              void* d_out, int out_size, void* d_ws, size_t ws_size,
                              hipStream_t stream) {
    const float* x    = (const float*)d_in[0];
    const float* Wqkv = (const float*)d_in[1];
    const float* bqkv = (const float*)d_in[2];
    const float* Wo   = (const float*)d_in[3];
    const float* bo   = (const float*)d_in[4];
    float* out = (float*)d_out;

    char* ws = (char*)d_ws;
    ushort* x_bf   = (ushort*)(ws);                  // 16 MB
    ushort* wqkvT  = (ushort*)(ws + 16777216);       // 24 MB
    ushort* woT    = (ushort*)(ws + 41943040);       //  8 MB
    ushort* qkv_bf = (ushort*)(ws + 50331648);       // 48 MB: [4096][6144] bf16
    ushort* Qb     = (ushort*)(ws + 100663296);      // 16 MB: [32][2048][128]
    ushort* Kb     = (ushort*)(ws + 117440512);      // 16 MB
    ushort* VtG    = (ushort*)(ws + 134217728);      // 16 MB: [32][128][2048]
    ushort* ctx    = (ushort*)(ws + 150994944);      // 16 MB -> total 160 MB

    cvt_bf16_kernel<<<8192, 256, 0, stream>>>(x, x_bf, 2097152);
    transpose_bf16_kernel<<<dim3(192, 64), dim3(32, 8), 0, stream>>>(Wqkv, wqkvT, 2048, 6144);
    transpose_bf16_kernel<<<dim3(64, 64), dim3(32, 8), 0, stream>>>(Wo, woT, 2048, 2048);
    gemm_bt_bias<ushort><<<dim3(48, 32), 256, 0, stream>>>(x_bf, wqkvT, bqkv, qkv_bf, 4096, 6144, 2048);
    rope_cast_qk<<<32768, 256, 0, stream>>>(qkv_bf, Qb, Kb);
    v_transpose<<<dim3(64, 4, 32), dim3(32, 8), 0, stream>>>(qkv_bf, VtG);
    attn_mfma<<<dim3(16, 32), 256, 0, stream>>>(Qb, Kb, VtG, ctx);
    gemm_bt_bias<float><<<dim3(16, 32), 256, 0, stream>>>(ctx, woT, bo, out, 4096, 2048, 2048);
}

// Round 5
// 502.727 us; speedup vs baseline: 1.1490x; 1.1490x over previous
//
#include <hip/hip_runtime.h>
#include <hip/hip_bf16.h>
#include <cstdint>
#include <type_traits>

#define D_MODEL 2048
#define NH 16
#define HD 128
#define SEQ 2048
#define QKV_LD (3 * D_MODEL) // 6144

typedef __attribute__((ext_vector_type(8))) short short8;
typedef __attribute__((ext_vector_type(4))) float f32x4;
typedef __attribute__((ext_vector_type(16))) float f32x16;

__device__ __forceinline__ ushort f2bf(float f) {
    union { float f; uint32_t u; } c; c.f = f;
    uint32_t u = c.u;
    uint32_t r = (u + 0x7FFFu + ((u >> 16) & 1u)) >> 16;
    return (ushort)r;
}
__device__ __forceinline__ float bf2f(ushort b) {
    union { uint32_t u; float f; } c; c.u = ((uint32_t)b) << 16;
    return c.f;
}

// ---------------- fp32 -> bf16 cast (x) ----------------
__global__ void cvt_bf16_kernel(const float* __restrict__ in, ushort* __restrict__ out, int n4) {
    int idx = blockIdx.x * blockDim.x + threadIdx.x;
    if (idx >= n4) return;
    float4 v = ((const float4*)in)[idx];
    ushort4 o;
    o.x = f2bf(v.x); o.y = f2bf(v.y); o.z = f2bf(v.z); o.w = f2bf(v.w);
    ((ushort4*)out)[idx] = o;
}

// ---------------- fp32 [R][C] -> bf16 [C][R] transpose ----------------
__global__ void transpose_bf16_kernel(const float* __restrict__ in, ushort* __restrict__ out,
                                      int R, int C) {
    __shared__ float tile[32][33];
    int tx = threadIdx.x, ty = threadIdx.y; // 32 x 8
    int c0 = blockIdx.x * 32, r0 = blockIdx.y * 32;
    for (int i = 0; i < 4; ++i) {
        int r = r0 + ty + i * 8;
        tile[ty + i * 8][tx] = in[(size_t)r * C + c0 + tx];
    }
    __syncthreads();
    for (int i = 0; i < 4; ++i) {
        int c = c0 + ty + i * 8;
        out[(size_t)c * R + r0 + tx] = f2bf(tile[tx][ty + i * 8]);
    }
}

// ---------------- bf16 MFMA GEMM, VGPR-prefetch pipeline ----------------
// C[M][N] = A[M][K] * Bt[N][K]^T + bias ; 128x128 tile, BK=32, 4 waves
template <typename OutT>
__global__ __launch_bounds__(256) void gemm_bt_bias(
    const ushort* __restrict__ A,   // [M][K] bf16
    const ushort* __restrict__ Bt,  // [N][K] bf16
    const float* __restrict__ bias, // [N]
    OutT* __restrict__ C,           // [M][N] fp32 or bf16
    int M, int N, int K)
{
    __shared__ __align__(16) ushort As[128 * 32];
    __shared__ __align__(16) ushort Bs[128 * 32];
    int t = threadIdx.x;
    int m0 = blockIdx.y * 128, n0 = blockIdx.x * 128;
    int wave = t >> 6, lane = t & 63;
    int wm = (wave & 1) * 64, wn = (wave >> 1) * 64;
    int lr = lane & 15, lh = lane >> 4;

    f32x4 acc[4][4];
    for (int i = 0; i < 4; i++)
        for (int j = 0; j < 4; j++)
            acc[i][j] = (f32x4)0.0f;

    int srow = t >> 2;
    int scol = (t & 3) * 8;
    const ushort* Ag = A + (size_t)(m0 + srow) * K + scol;
    const ushort* Bg = Bt + (size_t)(n0 + srow) * K + scol;

    uint4 ar0 = *(const uint4*)(Ag);
    uint4 ar1 = *(const uint4*)(Ag + (size_t)64 * K);
    uint4 br0 = *(const uint4*)(Bg);
    uint4 br1 = *(const uint4*)(Bg + (size_t)64 * K);

    for (int k0 = 0; k0 < K; k0 += 32) {
        __syncthreads();
        *(uint4*)(As + srow * 32 + scol) = ar0;
        *(uint4*)(As + (srow + 64) * 32 + scol) = ar1;
        *(uint4*)(Bs + srow * 32 + scol) = br0;
        *(uint4*)(Bs + (srow + 64) * 32 + scol) = br1;
        __syncthreads();
        if (k0 + 32 < K) {
            ar0 = *(const uint4*)(Ag + k0 + 32);
            ar1 = *(const uint4*)(Ag + (size_t)64 * K + k0 + 32);
            br0 = *(const uint4*)(Bg + k0 + 32);
            br1 = *(const uint4*)(Bg + (size_t)64 * K + k0 + 32);
        }
        short8 a[4], b[4];
        for (int i = 0; i < 4; i++)
            a[i] = *(const short8*)(As + (wm + i * 16 + lr) * 32 + lh * 8);
        for (int j = 0; j < 4; j++)
            b[j] = *(const short8*)(Bs + (wn + j * 16 + lr) * 32 + lh * 8);
        for (int i = 0; i < 4; i++)
            for (int j = 0; j < 4; j++)
                acc[i][j] = __builtin_amdgcn_mfma_f32_16x16x32_bf16(a[i], b[j], acc[i][j], 0, 0, 0);
    }

    for (int i = 0; i < 4; i++) {
        int row = m0 + wm + i * 16 + lh * 4;
        for (int j = 0; j < 4; j++) {
            int col = n0 + wn + j * 16 + lr;
            float bv = bias[col];
            for (int r = 0; r < 4; r++) {
                float v = acc[i][j][r] + bv;
                if constexpr (std::is_same<OutT, ushort>::value)
                    C[(size_t)(row + r) * N + col] = f2bf(v);
                else
                    C[(size_t)(row + r) * N + col] = v;
            }
        }
    }
}

// ---------------- RoPE + cast + reshape: qkv_bf16 -> Qb,Kb [bh][s][128] (linear) ----------------
__global__ void rope_cast_qk(const ushort* __restrict__ qkv,
                             ushort* __restrict__ Qb, ushort* __restrict__ Kb) {
    int t = threadIdx.x;
    int wv = blockIdx.x * 4 + (t >> 6); // 0..131071
    int j = t & 63;
    int bs = wv >> 5;
    int rem = wv & 31;
    int which = rem >> 4;  // 0=q, 1=k (wave-uniform)
    int h = rem & 15;
    int s = bs & 2047;
    int b = bs >> 11;
    size_t src = (size_t)bs * QKV_LD + which * D_MODEL + h * HD;
    uint32_t pr = *(const uint32_t*)(qkv + src + 2 * j);
    float x1 = bf2f((ushort)(pr & 0xffff));
    float x2 = bf2f((ushort)(pr >> 16));
    float theta = powf(10000.0f, -(float)j * (1.0f / 64.0f));
    float ang = (float)s * theta;
    float sn, cs;
    sincosf(ang, &sn, &cs);
    float sc = which ? 1.0f : 0.08838834764831845f;
    float o1 = (x1 * cs - x2 * sn) * sc;
    float o2 = (x1 * sn + x2 * cs) * sc;
    ushort* dst = which ? Kb : Qb;
    size_t obase = ((size_t)(b * NH + h) * SEQ + s) * HD;
    dst[obase + j] = f2bf(o1);
    dst[obase + 64 + j] = f2bf(o2);
}

// ---------------- V transpose: qkv_bf16 v-part -> Vt [bh][d=128][s=2048] (linear) ----------------
__global__ void v_transpose(const ushort* __restrict__ qkv, ushort* __restrict__ Vt) {
    __shared__ ushort tile[32][33];
    int tx = threadIdx.x, ty = threadIdx.y; // 32 x 8
    int s0 = blockIdx.x * 32;
    int d0 = blockIdx.y * 32;
    int bh = blockIdx.z;
    int b = bh >> 4, h = bh & 15;
    for (int i = 0; i < 4; ++i) {
        int s = s0 + ty + i * 8;
        tile[ty + i * 8][tx] = qkv[((size_t)(b * SEQ + s)) * QKV_LD + 2 * D_MODEL + h * HD + d0 + tx];
    }
    __syncthreads();
    for (int i = 0; i < 4; ++i) {
        int d = d0 + ty + i * 8;
        Vt[((size_t)bh * HD + d) * SEQ + s0 + tx] = tile[tx][ty + i * 8];
    }
}

// ---------------- MFMA flash attention, VGPR-prefetch pipeline ----------------
// 4 waves x 32q (q-tile 128), key-tile 64, single-buffered LDS (50 KB).
// waves_per_eu pinned to 2 (cap 256 unified regs, 2 blocks/CU) — R4's spill
// came from the allocator targeting 3 waves/EU under a min-only hint.
// Per iter: B1 -> regs->LDS -> B2 -> issue loads(i+1) -> S^T+softmax+PV.
__global__ __launch_bounds__(256)
__attribute__((amdgpu_waves_per_eu(2, 2)))
void attn_mfma(const ushort* __restrict__ Qb,
               const ushort* __restrict__ Kb,
               const ushort* __restrict__ Vt,
               ushort* __restrict__ ctx) {
    __shared__ __align__(16) ushort smem[25600]; // Ks[0,8192) Vts[8192,16384) Ps[16384,25600)
    ushort* Ks  = smem;          // [64][128], 16B chunk c at c^(r&15)
    ushort* Vts = smem + 8192;   // [128][64], 16B chunk c at c^(d&7)
    ushort* Ps  = smem + 16384;  // [128][72]

    int t = threadIdx.x;
    int w = t >> 6, l = t & 63;
    int l31 = l & 31, g = l >> 5;
    int q0 = blockIdx.x * 128;
    int bh = blockIdx.y;
    int b = bh >> 4, h = bh & 15;

    const ushort* KgB = Kb + (size_t)bh * SEQ * HD;
    const ushort* VtB = Vt + (size_t)bh * HD * SEQ;

    int qrow = q0 + w * 32 + l31;
    const ushort* Qg = Qb + ((size_t)bh * SEQ + qrow) * HD;
    short8 qf[8];
#pragma unroll
    for (int kc = 0; kc < 8; kc++)
        qf[kc] = *(const short8*)(Qg + kc * 16 + g * 8);

    f32x16 O[4];
#pragma unroll
    for (int di = 0; di < 4; di++) O[di] = (f32x16)0.0f;
    float m_run = -INFINITY, l_run = 0.0f;

    // scalar per-thread staging offsets; per-chunk c2 terms are compile-time:
    //   K: global += c2*2048, lds += c2*2048 ; V: global += c2*65536, lds += c2*2048
    // (swizzle terms r&15 = t>>4 and d&7 = (t>>3)&7 are c2-independent)
    const int Kgoff = (t >> 4) * HD + (t & 15) * 8;
    const int Kloff = (t >> 4) * 128 + ((t & 15) ^ (t >> 4)) * 8;
    const int Vgoff = (t >> 3) * SEQ + (t & 7) * 8;
    const int Vloff = (t >> 3) * 64 + ((t & 7) ^ ((t >> 3) & 7)) * 8;

    uint4 kreg[4], vreg[4];
#pragma unroll
    for (int c2 = 0; c2 < 4; c2++) {
        kreg[c2] = *(const uint4*)(KgB + Kgoff + c2 * 2048);
        vreg[c2] = *(const uint4*)(VtB + Vgoff + c2 * 65536);
    }

    for (int it = 0; it < SEQ / 64; it++) {
        int k0 = it * 64;
        __syncthreads(); // B1: prev iter's LDS consumers done
#pragma unroll
        for (int c2 = 0; c2 < 4; c2++) {
            *(uint4*)(Ks + Kloff + c2 * 2048) = kreg[c2];
            *(uint4*)(Vts + Vloff + c2 * 2048) = vreg[c2];
        }
        __syncthreads(); // B2: tiles visible
        if (it + 1 < SEQ / 64) {
            const ushort* kp = KgB + (size_t)(k0 + 64) * HD + Kgoff;
            const ushort* vp = VtB + (k0 + 64) + Vgoff;
#pragma unroll
            for (int c2 = 0; c2 < 4; c2++) {
                kreg[c2] = *(const uint4*)(kp + c2 * 2048);
                vreg[c2] = *(const uint4*)(vp + c2 * 65536);
            }
        }

        // S^T = K · Q^T : [64 keys][32 q] per wave, 2 tiles of 32x32
        f32x16 St[2];
        St[0] = (f32x16)0.0f;
        St[1] = (f32x16)0.0f;
#pragma unroll
        for (int ki = 0; ki < 2; ki++) {
            int row = ki * 32 + l31;
#pragma unroll
            for (int kc = 0; kc < 8; kc++) {
                int cp = (kc * 2 + g) ^ (row & 15);
                short8 a = *(const short8*)(Ks + row * 128 + cp * 8);
                St[ki] = __builtin_amdgcn_mfma_f32_32x32x16_bf16(a, qf[kc], St[ki], 0, 0, 0);
            }
        }

        // online softmax (keys in regs, q = lane)
        float mx = -INFINITY;
#pragma unroll
        for (int ki = 0; ki < 2; ki++)
#pragma unroll
            for (int r = 0; r < 16; r++) mx = fmaxf(mx, St[ki][r]);
        mx = fmaxf(mx, __shfl_xor(mx, 32));
        float mn = fmaxf(m_run, mx);
        float alpha = __expf(m_run - mn);
        m_run = mn;
        float psum = 0.0f;
#pragma unroll
        for (int ki = 0; ki < 2; ki++)
#pragma unroll
            for (int r = 0; r < 16; r++) {
                float p = __expf(St[ki][r] - mn);
                St[ki][r] = p;
                psum += p;
            }
        psum += __shfl_xor(psum, 32);
        l_run = l_run * alpha + psum;
#pragma unroll
        for (int di = 0; di < 4; di++)
#pragma unroll
            for (int r = 0; r < 16; r++) O[di][r] *= alpha;

        // P (bf16) -> LDS, wave-private rows (same-wave ordering; no barrier)
        {
            int qloc = w * 32 + l31;
            ushort* Pr = Ps + qloc * 72;
#pragma unroll
            for (int ki = 0; ki < 2; ki++)
#pragma unroll
                for (int u = 0; u < 4; u++) {
                    ushort4 pk;
                    pk.x = f2bf(St[ki][4 * u + 0]);
                    pk.y = f2bf(St[ki][4 * u + 1]);
                    pk.z = f2bf(St[ki][4 * u + 2]);
                    pk.w = f2bf(St[ki][4 * u + 3]);
                    *(ushort4*)(Pr + ki * 32 + 8 * u + 4 * g) = pk;
                }
        }

        // O^T += V^T · P^T : [128 d][32 q] per wave
        {
            int qloc = w * 32 + l31;
            short8 pb[4];
#pragma unroll
            for (int kc = 0; kc < 4; kc++)
                pb[kc] = *(const short8*)(Ps + qloc * 72 + kc * 16 + g * 8);
#pragma unroll
            for (int di = 0; di < 4; di++) {
                int d = di * 32 + l31;
#pragma unroll
                for (int kc = 0; kc < 4; kc++) {
                    int cp = (kc * 2 + g) ^ (d & 7);
                    short8 va = *(const short8*)(Vts + d * 64 + cp * 8);
                    O[di] = __builtin_amdgcn_mfma_f32_32x32x16_bf16(va, pb[kc], O[di], 0, 0, 0);
                }
            }
        }
    }

    // epilogue: normalize, transpose through LDS, coalesced store
    __syncthreads();
    float inv = 1.0f / l_run;
    ushort* ob = smem; // [128][128]
    {
        int qloc = w * 32 + l31;
        ushort* orow = ob + qloc * 128;
#pragma unroll
        for (int di = 0; di < 4; di++)
#pragma unroll
            for (int u = 0; u < 4; u++) {
                ushort4 pk;
                pk.x = f2bf(O[di][4 * u + 0] * inv);
                pk.y = f2bf(O[di][4 * u + 1] * inv);
                pk.z = f2bf(O[di][4 * u + 2] * inv);
                pk.w = f2bf(O[di][4 * u + 3] * inv);
                *(ushort4*)(orow + di * 32 + 8 * u + 4 * g) = pk;
            }
    }
#pragma unroll
    for (int p = 0; p < 8; p++) {
        int qloc = w * 32 + p * 4 + (l >> 4);
        int c16 = l & 15;
        uint4 v = *(const uint4*)(ob + qloc * 128 + c16 * 8);
        size_t tok = (size_t)b * SEQ + q0 + qloc;
        *(uint4*)(ctx + tok * D_MODEL + h * HD + c16 * 8) = v;
    }
}

extern "C" void kernel_launch(void* const* d_in, const int* in_sizes, int n_in,
                              void* d_out, int out_size, void* d_ws, size_t ws_size,
                              hipStream_t stream) {
    const float* x    = (const float*)d_in[0];
    const float* Wqkv = (const float*)d_in[1];
    const float* bqkv = (const float*)d_in[2];
    const float* Wo   = (const float*)d_in[3];
    const float* bo   = (const float*)d_in[4];
    float* out = (float*)d_out;

    char* ws = (char*)d_ws;
    ushort* x_bf   = (ushort*)(ws);                  // 16 MB
    ushort* wqkvT  = (ushort*)(ws + 16777216);       // 24 MB
    ushort* woT    = (ushort*)(ws + 41943040);       //  8 MB
    ushort* qkv_bf = (ushort*)(ws + 50331648);       // 48 MB: [4096][6144] bf16
    ushort* Qb     = (ushort*)(ws + 100663296);      // 16 MB: [32][2048][128]
    ushort* Kb     = (ushort*)(ws + 117440512);      // 16 MB
    ushort* VtG    = (ushort*)(ws + 134217728);      // 16 MB: [32][128][2048]
    ushort* ctx    = (ushort*)(ws + 150994944);      // 16 MB -> total 160 MB

    cvt_bf16_kernel<<<8192, 256, 0, stream>>>(x, x_bf, 2097152);
    transpose_bf16_kernel<<<dim3(192, 64), dim3(32, 8), 0, stream>>>(Wqkv, wqkvT, 2048, 6144);
    transpose_bf16_kernel<<<dim3(64, 64), dim3(32, 8), 0, stream>>>(Wo, woT, 2048, 2048);
    gemm_bt_bias<ushort><<<dim3(48, 32), 256, 0, stream>>>(x_bf, wqkvT, bqkv, qkv_bf, 4096, 6144, 2048);
    rope_cast_qk<<<32768, 256, 0, stream>>>(qkv_bf, Qb, Kb);
    v_transpose<<<dim3(64, 4, 32), dim3(32, 8), 0, stream>>>(qkv_bf, VtG);
    attn_mfma<<<dim3(16, 32), 256, 0, stream>>>(Qb, Kb, VtG, ctx);
    gemm_bt_bias<float><<<dim3(16, 32), 256, 0, stream>>>(ctx, woT, bo, out, 4096, 2048, 2048);
}

// Round 6
// 485.263 us; speedup vs baseline: 1.1903x; 1.0360x over previous
//
#include <hip/hip_runtime.h>
#include <hip/hip_bf16.h>
#include <cstdint>
#include <type_traits>

#define D_MODEL 2048
#define NH 16
#define HD 128
#define SEQ 2048
#define QKV_LD (3 * D_MODEL) // 6144

typedef __attribute__((ext_vector_type(8))) short short8;
typedef __attribute__((ext_vector_type(4))) float f32x4;
typedef __attribute__((ext_vector_type(16))) float f32x16;

__device__ __forceinline__ ushort f2bf(float f) {
    union { float f; uint32_t u; } c; c.f = f;
    uint32_t u = c.u;
    uint32_t r = (u + 0x7FFFu + ((u >> 16) & 1u)) >> 16;
    return (ushort)r;
}
__device__ __forceinline__ float bf2f(ushort b) {
    union { uint32_t u; float f; } c; c.u = ((uint32_t)b) << 16;
    return c.f;
}

// ---------------- fp32 -> bf16 cast (x) ----------------
__global__ void cvt_bf16_kernel(const float* __restrict__ in, ushort* __restrict__ out, int n4) {
    int idx = blockIdx.x * blockDim.x + threadIdx.x;
    if (idx >= n4) return;
    float4 v = ((const float4*)in)[idx];
    ushort4 o;
    o.x = f2bf(v.x); o.y = f2bf(v.y); o.z = f2bf(v.z); o.w = f2bf(v.w);
    ((ushort4*)out)[idx] = o;
}

// ---------------- fp32 [R][C] -> bf16 [C][R] transpose ----------------
__global__ void transpose_bf16_kernel(const float* __restrict__ in, ushort* __restrict__ out,
                                      int R, int C) {
    __shared__ float tile[32][33];
    int tx = threadIdx.x, ty = threadIdx.y; // 32 x 8
    int c0 = blockIdx.x * 32, r0 = blockIdx.y * 32;
    for (int i = 0; i < 4; ++i) {
        int r = r0 + ty + i * 8;
        tile[ty + i * 8][tx] = in[(size_t)r * C + c0 + tx];
    }
    __syncthreads();
    for (int i = 0; i < 4; ++i) {
        int c = c0 + ty + i * 8;
        out[(size_t)c * R + r0 + tx] = f2bf(tile[tx][ty + i * 8]);
    }
}

// ---------------- bf16 MFMA GEMM, VGPR-prefetch pipeline ----------------
// C[M][N] = A[M][K] * Bt[N][K]^T + bias ; 128x128 tile, BK=32, 4 waves
template <typename OutT>
__global__ __launch_bounds__(256) void gemm_bt_bias(
    const ushort* __restrict__ A,   // [M][K] bf16
    const ushort* __restrict__ Bt,  // [N][K] bf16
    const float* __restrict__ bias, // [N]
    OutT* __restrict__ C,           // [M][N] fp32 or bf16
    int M, int N, int K)
{
    __shared__ __align__(16) ushort As[128 * 32];
    __shared__ __align__(16) ushort Bs[128 * 32];
    int t = threadIdx.x;
    int m0 = blockIdx.y * 128, n0 = blockIdx.x * 128;
    int wave = t >> 6, lane = t & 63;
    int wm = (wave & 1) * 64, wn = (wave >> 1) * 64;
    int lr = lane & 15, lh = lane >> 4;

    f32x4 acc[4][4];
    for (int i = 0; i < 4; i++)
        for (int j = 0; j < 4; j++)
            acc[i][j] = (f32x4)0.0f;

    int srow = t >> 2;
    int scol = (t & 3) * 8;
    const ushort* Ag = A + (size_t)(m0 + srow) * K + scol;
    const ushort* Bg = Bt + (size_t)(n0 + srow) * K + scol;

    uint4 ar0 = *(const uint4*)(Ag);
    uint4 ar1 = *(const uint4*)(Ag + (size_t)64 * K);
    uint4 br0 = *(const uint4*)(Bg);
    uint4 br1 = *(const uint4*)(Bg + (size_t)64 * K);

    for (int k0 = 0; k0 < K; k0 += 32) {
        __syncthreads();
        *(uint4*)(As + srow * 32 + scol) = ar0;
        *(uint4*)(As + (srow + 64) * 32 + scol) = ar1;
        *(uint4*)(Bs + srow * 32 + scol) = br0;
        *(uint4*)(Bs + (srow + 64) * 32 + scol) = br1;
        __syncthreads();
        if (k0 + 32 < K) {
            ar0 = *(const uint4*)(Ag + k0 + 32);
            ar1 = *(const uint4*)(Ag + (size_t)64 * K + k0 + 32);
            br0 = *(const uint4*)(Bg + k0 + 32);
            br1 = *(const uint4*)(Bg + (size_t)64 * K + k0 + 32);
        }
        short8 a[4], b[4];
        for (int i = 0; i < 4; i++)
            a[i] = *(const short8*)(As + (wm + i * 16 + lr) * 32 + lh * 8);
        for (int j = 0; j < 4; j++)
            b[j] = *(const short8*)(Bs + (wn + j * 16 + lr) * 32 + lh * 8);
        for (int i = 0; i < 4; i++)
            for (int j = 0; j < 4; j++)
                acc[i][j] = __builtin_amdgcn_mfma_f32_16x16x32_bf16(a[i], b[j], acc[i][j], 0, 0, 0);
    }

    for (int i = 0; i < 4; i++) {
        int row = m0 + wm + i * 16 + lh * 4;
        for (int j = 0; j < 4; j++) {
            int col = n0 + wn + j * 16 + lr;
            float bv = bias[col];
            for (int r = 0; r < 4; r++) {
                float v = acc[i][j][r] + bv;
                if constexpr (std::is_same<OutT, ushort>::value)
                    C[(size_t)(row + r) * N + col] = f2bf(v);
                else
                    C[(size_t)(row + r) * N + col] = v;
            }
        }
    }
}

// ---------------- RoPE + cast + reshape: qkv_bf16 -> Qb,Kb [bh][s][128] (linear) ----------------
__global__ void rope_cast_qk(const ushort* __restrict__ qkv,
                             ushort* __restrict__ Qb, ushort* __restrict__ Kb) {
    int t = threadIdx.x;
    int wv = blockIdx.x * 4 + (t >> 6); // 0..131071
    int j = t & 63;
    int bs = wv >> 5;
    int rem = wv & 31;
    int which = rem >> 4;  // 0=q, 1=k (wave-uniform)
    int h = rem & 15;
    int s = bs & 2047;
    int b = bs >> 11;
    size_t src = (size_t)bs * QKV_LD + which * D_MODEL + h * HD;
    uint32_t pr = *(const uint32_t*)(qkv + src + 2 * j);
    float x1 = bf2f((ushort)(pr & 0xffff));
    float x2 = bf2f((ushort)(pr >> 16));
    float theta = powf(10000.0f, -(float)j * (1.0f / 64.0f));
    float ang = (float)s * theta;
    float sn, cs;
    sincosf(ang, &sn, &cs);
    float sc = which ? 1.0f : 0.08838834764831845f;
    float o1 = (x1 * cs - x2 * sn) * sc;
    float o2 = (x1 * sn + x2 * cs) * sc;
    ushort* dst = which ? Kb : Qb;
    size_t obase = ((size_t)(b * NH + h) * SEQ + s) * HD;
    dst[obase + j] = f2bf(o1);
    dst[obase + 64 + j] = f2bf(o2);
}

// ---------------- V transpose: qkv_bf16 v-part -> Vt [bh][d=128][s=2048] (linear) ----------------
__global__ void v_transpose(const ushort* __restrict__ qkv, ushort* __restrict__ Vt) {
    __shared__ ushort tile[32][33];
    int tx = threadIdx.x, ty = threadIdx.y; // 32 x 8
    int s0 = blockIdx.x * 32;
    int d0 = blockIdx.y * 32;
    int bh = blockIdx.z;
    int b = bh >> 4, h = bh & 15;
    for (int i = 0; i < 4; ++i) {
        int s = s0 + ty + i * 8;
        tile[ty + i * 8][tx] = qkv[((size_t)(b * SEQ + s)) * QKV_LD + 2 * D_MODEL + h * HD + d0 + tx];
    }
    __syncthreads();
    for (int i = 0; i < 4; ++i) {
        int d = d0 + ty + i * 8;
        Vt[((size_t)bh * HD + d) * SEQ + s0 + tx] = tile[tx][ty + i * 8];
    }
}

// ---------------- MFMA flash attention, VGPR-prefetch pipeline ----------------
// 4 waves x 32q (q-tile 128), key-tile 64, single-buffered LDS (50 KB).
// Prefetch regs are 8 NAMED uint4s (no alloca -> no LDS promotion, no spill
// from array coloring). No occupancy attribute: natural allocation (R2-style).
// Per iter: B1 -> regs->LDS -> B2 -> issue loads(i+1, wrapped addr) -> compute.
__global__ __launch_bounds__(256)
void attn_mfma(const ushort* __restrict__ Qb,
               const ushort* __restrict__ Kb,
               const ushort* __restrict__ Vt,
               ushort* __restrict__ ctx) {
    __shared__ __align__(16) ushort smem[25600]; // Ks[0,8192) Vts[8192,16384) Ps[16384,25600)
    ushort* Ks  = smem;          // [64][128], 16B chunk c at c^(r&15)
    ushort* Vts = smem + 8192;   // [128][64], 16B chunk c at c^(d&7)
    ushort* Ps  = smem + 16384;  // [128][72]

    int t = threadIdx.x;
    int w = t >> 6, l = t & 63;
    int l31 = l & 31, g = l >> 5;
    int q0 = blockIdx.x * 128;
    int bh = blockIdx.y;
    int b = bh >> 4, h = bh & 15;

    const ushort* KgB = Kb + (size_t)bh * SEQ * HD;
    const ushort* VtB = Vt + (size_t)bh * HD * SEQ;

    int qrow = q0 + w * 32 + l31;
    const ushort* Qg = Qb + ((size_t)bh * SEQ + qrow) * HD;
    short8 qf[8];
#pragma unroll
    for (int kc = 0; kc < 8; kc++)
        qf[kc] = *(const short8*)(Qg + kc * 16 + g * 8);

    f32x16 O[4];
#pragma unroll
    for (int di = 0; di < 4; di++) O[di] = (f32x16)0.0f;
    float m_run = -INFINITY, l_run = 0.0f;

    // scalar per-thread staging offsets (c2 terms are compile-time constants):
    //   K: global += c2*2048, lds += c2*2048 ; V: global += c2*65536, lds += c2*2048
    const int Kgoff = (t >> 4) * HD + (t & 15) * 8;
    const int Kloff = (t >> 4) * 128 + ((t & 15) ^ (t >> 4)) * 8;
    const int Vgoff = (t >> 3) * SEQ + (t & 7) * 8;
    const int Vloff = (t >> 3) * 64 + ((t & 7) ^ ((t >> 3) & 7)) * 8;

    uint4 k0r, k1r, k2r, k3r, v0r, v1r, v2r, v3r;
    {
        const ushort* kp = KgB + Kgoff;
        const ushort* vp = VtB + Vgoff;
        k0r = *(const uint4*)(kp);
        k1r = *(const uint4*)(kp + 2048);
        k2r = *(const uint4*)(kp + 4096);
        k3r = *(const uint4*)(kp + 6144);
        v0r = *(const uint4*)(vp);
        v1r = *(const uint4*)(vp + 65536);
        v2r = *(const uint4*)(vp + 131072);
        v3r = *(const uint4*)(vp + 196608);
    }

    for (int it = 0; it < SEQ / 64; it++) {
        int k0 = it * 64;
        __syncthreads(); // B1: prev iter's LDS consumers done
        *(uint4*)(Ks + Kloff)          = k0r;
        *(uint4*)(Ks + Kloff + 2048)   = k1r;
        *(uint4*)(Ks + Kloff + 4096)   = k2r;
        *(uint4*)(Ks + Kloff + 6144)   = k3r;
        *(uint4*)(Vts + Vloff)         = v0r;
        *(uint4*)(Vts + Vloff + 2048)  = v1r;
        *(uint4*)(Vts + Vloff + 4096)  = v2r;
        *(uint4*)(Vts + Vloff + 6144)  = v3r;
        __syncthreads(); // B2: tiles visible
        {
            int knext = (k0 + 64) & (SEQ - 1); // wrap: always-valid prefetch
            const ushort* kp = KgB + (size_t)knext * HD + Kgoff;
            const ushort* vp = VtB + knext + Vgoff;
            k0r = *(const uint4*)(kp);
            k1r = *(const uint4*)(kp + 2048);
            k2r = *(const uint4*)(kp + 4096);
            k3r = *(const uint4*)(kp + 6144);
            v0r = *(const uint4*)(vp);
            v1r = *(const uint4*)(vp + 65536);
            v2r = *(const uint4*)(vp + 131072);
            v3r = *(const uint4*)(vp + 196608);
        }

        // S^T = K · Q^T : [64 keys][32 q] per wave, 2 tiles of 32x32
        f32x16 St[2];
        St[0] = (f32x16)0.0f;
        St[1] = (f32x16)0.0f;
#pragma unroll
        for (int ki = 0; ki < 2; ki++) {
            int row = ki * 32 + l31;
#pragma unroll
            for (int kc = 0; kc < 8; kc++) {
                int cp = (kc * 2 + g) ^ (row & 15);
                short8 a = *(const short8*)(Ks + row * 128 + cp * 8);
                St[ki] = __builtin_amdgcn_mfma_f32_32x32x16_bf16(a, qf[kc], St[ki], 0, 0, 0);
            }
        }

        // online softmax (keys in regs, q = lane)
        float mx = -INFINITY;
#pragma unroll
        for (int ki = 0; ki < 2; ki++)
#pragma unroll
            for (int r = 0; r < 16; r++) mx = fmaxf(mx, St[ki][r]);
        mx = fmaxf(mx, __shfl_xor(mx, 32));
        float mn = fmaxf(m_run, mx);
        float alpha = __expf(m_run - mn);
        m_run = mn;
        float psum = 0.0f;
#pragma unroll
        for (int ki = 0; ki < 2; ki++)
#pragma unroll
            for (int r = 0; r < 16; r++) {
                float p = __expf(St[ki][r] - mn);
                St[ki][r] = p;
                psum += p;
            }
        psum += __shfl_xor(psum, 32);
        l_run = l_run * alpha + psum;
#pragma unroll
        for (int di = 0; di < 4; di++)
#pragma unroll
            for (int r = 0; r < 16; r++) O[di][r] *= alpha;

        // P (bf16) -> LDS, wave-private rows (same-wave ordering; no barrier)
        {
            int qloc = w * 32 + l31;
            ushort* Pr = Ps + qloc * 72;
#pragma unroll
            for (int ki = 0; ki < 2; ki++)
#pragma unroll
                for (int u = 0; u < 4; u++) {
                    ushort4 pk;
                    pk.x = f2bf(St[ki][4 * u + 0]);
                    pk.y = f2bf(St[ki][4 * u + 1]);
                    pk.z = f2bf(St[ki][4 * u + 2]);
                    pk.w = f2bf(St[ki][4 * u + 3]);
                    *(ushort4*)(Pr + ki * 32 + 8 * u + 4 * g) = pk;
                }
        }

        // O^T += V^T · P^T : [128 d][32 q] per wave
        {
            int qloc = w * 32 + l31;
            short8 pb[4];
#pragma unroll
            for (int kc = 0; kc < 4; kc++)
                pb[kc] = *(const short8*)(Ps + qloc * 72 + kc * 16 + g * 8);
#pragma unroll
            for (int di = 0; di < 4; di++) {
                int d = di * 32 + l31;
#pragma unroll
                for (int kc = 0; kc < 4; kc++) {
                    int cp = (kc * 2 + g) ^ (d & 7);
                    short8 va = *(const short8*)(Vts + d * 64 + cp * 8);
                    O[di] = __builtin_amdgcn_mfma_f32_32x32x16_bf16(va, pb[kc], O[di], 0, 0, 0);
                }
            }
        }
    }

    // epilogue: normalize, transpose through LDS, coalesced store
    __syncthreads();
    float inv = 1.0f / l_run;
    ushort* ob = smem; // [128][128]
    {
        int qloc = w * 32 + l31;
        ushort* orow = ob + qloc * 128;
#pragma unroll
        for (int di = 0; di < 4; di++)
#pragma unroll
            for (int u = 0; u < 4; u++) {
                ushort4 pk;
                pk.x = f2bf(O[di][4 * u + 0] * inv);
                pk.y = f2bf(O[di][4 * u + 1] * inv);
                pk.z = f2bf(O[di][4 * u + 2] * inv);
                pk.w = f2bf(O[di][4 * u + 3] * inv);
                *(ushort4*)(orow + di * 32 + 8 * u + 4 * g) = pk;
            }
    }
#pragma unroll
    for (int p = 0; p < 8; p++) {
        int qloc = w * 32 + p * 4 + (l >> 4);
        int c16 = l & 15;
        uint4 v = *(const uint4*)(ob + qloc * 128 + c16 * 8);
        size_t tok = (size_t)b * SEQ + q0 + qloc;
        *(uint4*)(ctx + tok * D_MODEL + h * HD + c16 * 8) = v;
    }
}

extern "C" void kernel_launch(void* const* d_in, const int* in_sizes, int n_in,
                              void* d_out, int out_size, void* d_ws, size_t ws_size,
                              hipStream_t stream) {
    const float* x    = (const float*)d_in[0];
    const float* Wqkv = (const float*)d_in[1];
    const float* bqkv = (const float*)d_in[2];
    const float* Wo   = (const float*)d_in[3];
    const float* bo   = (const float*)d_in[4];
    float* out = (float*)d_out;

    char* ws = (char*)d_ws;
    ushort* x_bf   = (ushort*)(ws);                  // 16 MB
    ushort* wqkvT  = (ushort*)(ws + 16777216);       // 24 MB
    ushort* woT    = (ushort*)(ws + 41943040);       //  8 MB
    ushort* qkv_bf = (ushort*)(ws + 50331648);       // 48 MB: [4096][6144] bf16
    ushort* Qb     = (ushort*)(ws + 100663296);      // 16 MB: [32][2048][128]
    ushort* Kb     = (ushort*)(ws + 117440512);      // 16 MB
    ushort* VtG    = (ushort*)(ws + 134217728);      // 16 MB: [32][128][2048]
    ushort* ctx    = (ushort*)(ws + 150994944);      // 16 MB -> total 160 MB

    cvt_bf16_kernel<<<8192, 256, 0, stream>>>(x, x_bf, 2097152);
    transpose_bf16_kernel<<<dim3(192, 64), dim3(32, 8), 0, stream>>>(Wqkv, wqkvT, 2048, 6144);
    transpose_bf16_kernel<<<dim3(64, 64), dim3(32, 8), 0, stream>>>(Wo, woT, 2048, 2048);
    gemm_bt_bias<ushort><<<dim3(48, 32), 256, 0, stream>>>(x_bf, wqkvT, bqkv, qkv_bf, 4096, 6144, 2048);
    rope_cast_qk<<<32768, 256, 0, stream>>>(qkv_bf, Qb, Kb);
    v_transpose<<<dim3(64, 4, 32), dim3(32, 8), 0, stream>>>(qkv_bf, VtG);
    attn_mfma<<<dim3(16, 32), 256, 0, stream>>>(Qb, Kb, VtG, ctx);
    gemm_bt_bias<float><<<dim3(16, 32), 256, 0, stream>>>(ctx, woT, bo, out, 4096, 2048, 2048);
}